// Round 1
// baseline (212.863 us; speedup 1.0000x reference)
//
#include <hip/hip_runtime.h>

#define B_ 8
#define C_ 128
#define L_ 2048

typedef __attribute__((ext_vector_type(8))) short s8v;
typedef __attribute__((ext_vector_type(4))) short s4v;
typedef __attribute__((ext_vector_type(4))) float f4v;
typedef __attribute__((ext_vector_type(8))) float f8v;

static __device__ inline short f2bf(float f) {
    union { float f; unsigned u; } v; v.f = f;
    unsigned r = v.u + 0x7FFFu + ((v.u >> 16) & 1u);
    return (short)(r >> 16);
}

// ---------------------------------------------------------------------------
// Kernel A: h = relu(x); Q = (Wq h + bq) * scale  -> [B][L][C] bf16
//           K =  Wk h + bk                        -> [B][L][C] bf16
//           V =  Wv h + bv                        -> [B][C][L] bf16 (transposed)
// grid 256 = B * (L/64), block 256 (4 waves, each wave owns 16 l-rows)
// ---------------------------------------------------------------------------
__global__ __launch_bounds__(256) void qkv_proj(
    const float* __restrict__ x,
    const float* __restrict__ Wq, const float* __restrict__ bq,
    const float* __restrict__ Wk, const float* __restrict__ bk,
    const float* __restrict__ Wv, const float* __restrict__ bv,
    short* __restrict__ Qb, short* __restrict__ Kb, short* __restrict__ Vt)
{
    __shared__ short ht[64][136];      // [l][c] relu(x), padded +8 to dodge bank conflicts
    const int b  = blockIdx.x >> 5;
    const int l0 = (blockIdx.x & 31) * 64;
    const int tid = threadIdx.x;

    // stage relu(x) transposed: x is [C][L], coalesced along l
    {
        const int lq = (tid & 15) * 4;
        const int cb = tid >> 4;
        for (int p = 0; p < 8; ++p) {
            int c = p * 16 + cb;
            f4v v = *(const f4v*)(x + ((size_t)b * C_ + c) * L_ + l0 + lq);
#pragma unroll
            for (int j = 0; j < 4; ++j)
                ht[lq + j][c] = f2bf(v[j] > 0.f ? v[j] : 0.f);
        }
    }
    __syncthreads();

    const int lane = tid & 63, w = tid >> 6;
    const int lr = lane & 15, lg = lane >> 4;

    // A-fragments: lane holds H[row=lr][k = 32*kk + 8*lg + j]
    s8v hf[4];
#pragma unroll
    for (int kk = 0; kk < 4; ++kk)
        hf[kk] = *(const s8v*)&ht[w * 16 + lr][kk * 32 + lg * 8];

    const float scale = 0.08838834764831845f;  // 1/sqrt(128)
    const float* Ws[3] = { Wq, Wk, Wv };
    const float* Bs[3] = { bq, bk, bv };

#pragma unroll
    for (int mat = 0; mat < 3; ++mat) {
        const float* W    = Ws[mat];
        const float* bias = Bs[mat];
#pragma unroll
        for (int nt = 0; nt < 8; ++nt) {
            f4v acc = {0.f, 0.f, 0.f, 0.f};
#pragma unroll
            for (int kk = 0; kk < 4; ++kk) {
                // B-frag: lane holds W[o = nt*16+lr][c = 32*kk + 8*lg + j]
                f8v wv = *(const f8v*)(W + (size_t)(nt * 16 + lr) * C_ + kk * 32 + lg * 8);
                s8v wb;
#pragma unroll
                for (int j = 0; j < 8; ++j) wb[j] = f2bf(wv[j]);
                acc = __builtin_amdgcn_mfma_f32_16x16x32_bf16(hf[kk], wb, acc, 0, 0, 0);
            }
            const int o = nt * 16 + lr;
            const float bsc = bias[o];
            const int row = l0 + w * 16 + 4 * lg;   // + reg
            if (mat == 0) {
#pragma unroll
                for (int r = 0; r < 4; ++r)
                    Qb[((size_t)b * L_ + row + r) * C_ + o] = f2bf((acc[r] + bsc) * scale);
            } else if (mat == 1) {
#pragma unroll
                for (int r = 0; r < 4; ++r)
                    Kb[((size_t)b * L_ + row + r) * C_ + o] = f2bf(acc[r] + bsc);
            } else {
                s4v pk;
#pragma unroll
                for (int r = 0; r < 4; ++r) pk[r] = f2bf(acc[r] + bsc);
                *(s4v*)(Vt + ((size_t)b * C_ + o) * L_ + row) = pk;   // 8B store along l
            }
        }
    }
}

// ---------------------------------------------------------------------------
// Kernel B: flash attention + relu -> RR [B][L][C] bf16
// grid 256: blockIdx&7 = batch (XCD-local K/V reuse), >>3 = q-tile of 64 rows.
// 4 waves, each wave owns 16 q-rows; KV tiles of 32.
// ---------------------------------------------------------------------------
__global__ __launch_bounds__(256) void attn(
    const short* __restrict__ Qb, const short* __restrict__ Kb,
    const short* __restrict__ Vt, short* __restrict__ RR)
{
    __shared__ short pl[4][16 * 40];   // per-wave P tile, 40-col pitch
    const int b  = blockIdx.x & 7;
    const int q0 = (blockIdx.x >> 3) * 64;
    const int tid = threadIdx.x, lane = tid & 63, w = tid >> 6;
    const int lr = lane & 15, lg = lane >> 4;
    const int row0 = q0 + w * 16;
    const size_t LC = (size_t)L_ * C_;

    // Q fragments (scale pre-folded): lane holds Q[row0+lr][32*kk + 8*lg + j]
    s8v qf[4];
#pragma unroll
    for (int kk = 0; kk < 4; ++kk)
        qf[kk] = *(const s8v*)(Qb + (size_t)b * LC + (size_t)(row0 + lr) * C_ + kk * 32 + lg * 8);

    f4v of[8];
#pragma unroll
    for (int t = 0; t < 8; ++t) of[t] = (f4v){0.f, 0.f, 0.f, 0.f};
    float mrun[4], lsum[4];
#pragma unroll
    for (int r = 0; r < 4; ++r) { mrun[r] = -1e30f; lsum[r] = 0.f; }

    short* myp = &pl[w][0];
    const short* Kbase = Kb + (size_t)b * LC;
    const short* Vbase = Vt + (size_t)b * LC;

    for (int mt = 0; mt < 64; ++mt) {
        const int m0 = mt * 32;
        // S = Q K^T for 16 q-rows x 32 k-positions
        f4v s0 = {0.f,0.f,0.f,0.f}, s1 = {0.f,0.f,0.f,0.f};
#pragma unroll
        for (int kk = 0; kk < 4; ++kk) {
            s8v kf0 = *(const s8v*)(Kbase + (size_t)(m0 + lr) * C_ + kk * 32 + lg * 8);
            s0 = __builtin_amdgcn_mfma_f32_16x16x32_bf16(qf[kk], kf0, s0, 0, 0, 0);
            s8v kf1 = *(const s8v*)(Kbase + (size_t)(m0 + 16 + lr) * C_ + kk * 32 + lg * 8);
            s1 = __builtin_amdgcn_mfma_f32_16x16x32_bf16(qf[kk], kf1, s1, 0, 0, 0);
        }
        // online softmax (rows r live on 16-lane group lg; cols across lanes)
        float al[4], p0[4], p1[4];
#pragma unroll
        for (int r = 0; r < 4; ++r) {
            float rm = fmaxf(s0[r], s1[r]);
            rm = fmaxf(rm, __shfl_xor(rm, 1));
            rm = fmaxf(rm, __shfl_xor(rm, 2));
            rm = fmaxf(rm, __shfl_xor(rm, 4));
            rm = fmaxf(rm, __shfl_xor(rm, 8));
            float mn = fmaxf(mrun[r], rm);
            al[r] = __expf(mrun[r] - mn);
            p0[r] = __expf(s0[r] - mn);
            p1[r] = __expf(s1[r] - mn);
            float rs = p0[r] + p1[r];
            rs += __shfl_xor(rs, 1);
            rs += __shfl_xor(rs, 2);
            rs += __shfl_xor(rs, 4);
            rs += __shfl_xor(rs, 8);
            lsum[r] = lsum[r] * al[r] + rs;
            mrun[r] = mn;
        }
#pragma unroll
        for (int t = 0; t < 8; ++t) {
            of[t][0] *= al[0]; of[t][1] *= al[1];
            of[t][2] *= al[2]; of[t][3] *= al[3];
        }
        // P (C/D layout) -> LDS -> reload as A-frag layout
#pragma unroll
        for (int r = 0; r < 4; ++r) {
            const int row = 4 * lg + r;
            myp[row * 40 + lr]      = f2bf(p0[r]);
            myp[row * 40 + 16 + lr] = f2bf(p1[r]);
        }
        __syncthreads();   // fence: compiler must not hoist the read above writes
        s8v pf = *(const s8v*)(myp + lr * 40 + lg * 8);
        // PV: B-frag from transposed V, contiguous along m
#pragma unroll
        for (int t = 0; t < 8; ++t) {
            s8v vf = *(const s8v*)(Vbase + (size_t)(t * 16 + lr) * L_ + m0 + lg * 8);
            of[t] = __builtin_amdgcn_mfma_f32_16x16x32_bf16(pf, vf, of[t], 0, 0, 0);
        }
    }

#pragma unroll
    for (int r = 0; r < 4; ++r) lsum[r] = 1.0f / lsum[r];
#pragma unroll
    for (int t = 0; t < 8; ++t) {
#pragma unroll
        for (int r = 0; r < 4; ++r) {
            float v = of[t][r] * lsum[r];
            v = v > 0.f ? v : 0.f;   // relu(r) fused
            RR[(size_t)b * LC + (size_t)(row0 + 4 * lg + r) * C_ + t * 16 + lr] = f2bf(v);
        }
    }
}

// ---------------------------------------------------------------------------
// Kernel C: out = x + Wo @ RR^T + bo   -> [B][C][L] fp32
// ---------------------------------------------------------------------------
__global__ __launch_bounds__(256) void out_proj(
    const short* __restrict__ RR, const float* __restrict__ Wo,
    const float* __restrict__ bo, const float* __restrict__ x,
    float* __restrict__ out)
{
    const int b  = blockIdx.x >> 5;
    const int l0 = (blockIdx.x & 31) * 64;
    const int tid = threadIdx.x, lane = tid & 63, w = tid >> 6;
    const int lr = lane & 15, lg = lane >> 4;
    const size_t LC = (size_t)L_ * C_;
    const int row0 = l0 + w * 16;

    s8v af[4];
#pragma unroll
    for (int kk = 0; kk < 4; ++kk)
        af[kk] = *(const s8v*)(RR + (size_t)b * LC + (size_t)(row0 + lr) * C_ + kk * 32 + lg * 8);

#pragma unroll
    for (int nt = 0; nt < 8; ++nt) {
        f4v acc = {0.f, 0.f, 0.f, 0.f};
#pragma unroll
        for (int kk = 0; kk < 4; ++kk) {
            f8v wv = *(const f8v*)(Wo + (size_t)(nt * 16 + lr) * C_ + kk * 32 + lg * 8);
            s8v wb;
#pragma unroll
            for (int j = 0; j < 8; ++j) wb[j] = f2bf(wv[j]);
            acc = __builtin_amdgcn_mfma_f32_16x16x32_bf16(af[kk], wb, acc, 0, 0, 0);
        }
        const int o = nt * 16 + lr;
        const float bias = bo[o];
        const size_t base = (size_t)b * LC + (size_t)o * L_ + row0 + 4 * lg;
        f4v xv = *(const f4v*)(x + base);
        f4v ov;
#pragma unroll
        for (int r = 0; r < 4; ++r) ov[r] = acc[r] + xv[r] + bias;
        *(f4v*)(out + base) = ov;
    }
}

extern "C" void kernel_launch(void* const* d_in, const int* in_sizes, int n_in,
                              void* d_out, int out_size, void* d_ws, size_t ws_size,
                              hipStream_t stream) {
    const float* x  = (const float*)d_in[0];
    const float* Wq = (const float*)d_in[1];
    const float* bq = (const float*)d_in[2];
    const float* Wk = (const float*)d_in[3];
    const float* bk = (const float*)d_in[4];
    const float* Wv = (const float*)d_in[5];
    const float* bv = (const float*)d_in[6];
    const float* Wo = (const float*)d_in[7];
    const float* bo = (const float*)d_in[8];
    float* out = (float*)d_out;

    const size_t NE = (size_t)B_ * L_ * C_;   // 2,097,152 elements
    short* Qb = (short*)d_ws;                 // bf16 [B][L][C]
    short* Kb = Qb + NE;                      // bf16 [B][L][C]
    short* Vt = Kb + NE;                      // bf16 [B][C][L]
    short* RR = Vt + NE;                      // bf16 [B][L][C]

    qkv_proj<<<256, 256, 0, stream>>>(x, Wq, bq, Wk, bk, Wv, bv, Qb, Kb, Vt);
    attn    <<<256, 256, 0, stream>>>(Qb, Kb, Vt, RR);
    out_proj<<<256, 256, 0, stream>>>(RR, Wo, bo, x, out);
}

// Round 2
// 114.885 us; speedup vs baseline: 1.8528x; 1.8528x over previous
//
#include <hip/hip_runtime.h>

#define B_ 8
#define C_ 128
#define L_ 2048

typedef __attribute__((ext_vector_type(8))) short s8v;
typedef __attribute__((ext_vector_type(4))) short s4v;
typedef __attribute__((ext_vector_type(4))) float f4v;
typedef __attribute__((ext_vector_type(8))) float f8v;

static __device__ inline short f2bf(float f) {
    union { float f; unsigned u; } v; v.f = f;
    unsigned r = v.u + 0x7FFFu + ((v.u >> 16) & 1u);
    return (short)(r >> 16);
}

static __device__ inline void gload16(const void* g, void* l) {
    __builtin_amdgcn_global_load_lds(
        (const __attribute__((address_space(1))) unsigned int*)g,
        (__attribute__((address_space(3))) unsigned int*)l, 16, 0, 0);
}

#define WAIT_VM0 asm volatile("s_waitcnt vmcnt(0)" ::: "memory")
#define FENCE    asm volatile("" ::: "memory")

// ---------------------------------------------------------------------------
// Kernel A: h = relu(x); Q = (Wq h + bq) * scale  -> [B][L][C] bf16
//           K =  Wk h + bk                        -> [B][L][C] bf16
//           V =  Wv h + bv                        -> [B][C][L] bf16 (transposed)
// ---------------------------------------------------------------------------
__global__ __launch_bounds__(256) void qkv_proj(
    const float* __restrict__ x,
    const float* __restrict__ Wq, const float* __restrict__ bq,
    const float* __restrict__ Wk, const float* __restrict__ bk,
    const float* __restrict__ Wv, const float* __restrict__ bv,
    short* __restrict__ Qb, short* __restrict__ Kb, short* __restrict__ Vt)
{
    __shared__ short ht[64][136];
    const int b  = blockIdx.x >> 5;
    const int l0 = (blockIdx.x & 31) * 64;
    const int tid = threadIdx.x;

    {
        const int lq = (tid & 15) * 4;
        const int cb = tid >> 4;
        for (int p = 0; p < 8; ++p) {
            int c = p * 16 + cb;
            f4v v = *(const f4v*)(x + ((size_t)b * C_ + c) * L_ + l0 + lq);
#pragma unroll
            for (int j = 0; j < 4; ++j)
                ht[lq + j][c] = f2bf(v[j] > 0.f ? v[j] : 0.f);
        }
    }
    __syncthreads();

    const int lane = tid & 63, w = tid >> 6;
    const int lr = lane & 15, lg = lane >> 4;

    s8v hf[4];
#pragma unroll
    for (int kk = 0; kk < 4; ++kk)
        hf[kk] = *(const s8v*)&ht[w * 16 + lr][kk * 32 + lg * 8];

    const float scale = 0.08838834764831845f;  // 1/sqrt(128)
    const float* Ws[3] = { Wq, Wk, Wv };
    const float* Bs[3] = { bq, bk, bv };

#pragma unroll
    for (int mat = 0; mat < 3; ++mat) {
        const float* W    = Ws[mat];
        const float* bias = Bs[mat];
#pragma unroll
        for (int nt = 0; nt < 8; ++nt) {
            f4v acc = {0.f, 0.f, 0.f, 0.f};
#pragma unroll
            for (int kk = 0; kk < 4; ++kk) {
                f8v wv = *(const f8v*)(W + (size_t)(nt * 16 + lr) * C_ + kk * 32 + lg * 8);
                s8v wb;
#pragma unroll
                for (int j = 0; j < 8; ++j) wb[j] = f2bf(wv[j]);
                acc = __builtin_amdgcn_mfma_f32_16x16x32_bf16(hf[kk], wb, acc, 0, 0, 0);
            }
            const int o = nt * 16 + lr;
            const float bsc = bias[o];
            const int row = l0 + w * 16 + 4 * lg;
            if (mat == 0) {
#pragma unroll
                for (int r = 0; r < 4; ++r)
                    Qb[((size_t)b * L_ + row + r) * C_ + o] = f2bf((acc[r] + bsc) * scale);
            } else if (mat == 1) {
#pragma unroll
                for (int r = 0; r < 4; ++r)
                    Kb[((size_t)b * L_ + row + r) * C_ + o] = f2bf(acc[r] + bsc);
            } else {
                s4v pk;
#pragma unroll
                for (int r = 0; r < 4; ++r) pk[r] = f2bf(acc[r] + bsc);
                *(s4v*)(Vt + ((size_t)b * C_ + o) * L_ + row) = pk;
            }
        }
    }
}

// ---------------------------------------------------------------------------
// Kernel B: flash attention + relu -> RR [B][L][C] bf16
// 2-phase double-buffered pipeline: K/V tiles (KVBLK=64) staged block-wide
// into swizzled LDS via global_load_lds; prefetch tile t+1 before compute t;
// raw s_barrier + vmcnt(0) once per tile.
// ---------------------------------------------------------------------------
#define KVB 64
#define NT  (L_ / KVB)   // 32

__global__ __launch_bounds__(256) void attn(
    const short* __restrict__ Qb, const short* __restrict__ Kb,
    const short* __restrict__ Vt, short* __restrict__ RR)
{
    // K tile [64 rows][256B], swizzled: byte = row*256 + (colb ^ ((row&7)<<4))
    // V tile [128 c  ][128B], swizzled: byte = c*128   + (colb ^ ((c&7)<<4))
    __shared__ short kb[2][KVB * C_];
    __shared__ short vb[2][C_ * KVB];
    __shared__ short pl[4][16 * 72];

    const int b  = blockIdx.x & 7;
    const int q0 = (blockIdx.x >> 3) * 64;
    const int tid = threadIdx.x, lane = tid & 63, w = tid >> 6;
    const int lr = lane & 15, lg = lane >> 4;
    const int row0 = q0 + w * 16;
    const size_t LC = (size_t)L_ * C_;

    const short* Kbase = Kb + (size_t)b * LC;
    const short* Vbase = Vt + (size_t)b * LC;

    // precompute per-lane swizzled staging offsets (4 K issues + 4 V issues)
    int koff[4], ldso[4];
    size_t voff[4];
#pragma unroll
    for (int i = 0; i < 4; ++i) {
        const int p = w * 4096 + i * 1024 + lane * 16;   // linear LDS byte
        ldso[i] = w * 4096 + i * 1024;                   // wave-uniform dest base
        const int krow = p >> 8, kcol = p & 255;
        koff[i] = krow * 256 + (kcol ^ ((krow & 7) << 4));
        const int vc = p >> 7, vcol = p & 127;
        voff[i] = (size_t)vc * (L_ * 2) + (vcol ^ ((vc & 7) << 4));
    }

#define STAGE(nb, m0_) do {                                                   \
        const char* kg_ = (const char*)Kbase + (size_t)(m0_) * 256;           \
        const char* vg_ = (const char*)Vbase + (size_t)(m0_) * 2;             \
        char* kl_ = (char*)&kb[nb][0];                                        \
        char* vl_ = (char*)&vb[nb][0];                                        \
        _Pragma("unroll")                                                     \
        for (int i_ = 0; i_ < 4; ++i_) gload16(kg_ + koff[i_], kl_ + ldso[i_]); \
        _Pragma("unroll")                                                     \
        for (int i_ = 0; i_ < 4; ++i_) gload16(vg_ + voff[i_], vl_ + ldso[i_]); \
    } while (0)

    // Q fragments (scale pre-folded in kernel A)
    s8v qf[4];
#pragma unroll
    for (int kk = 0; kk < 4; ++kk)
        qf[kk] = *(const s8v*)(Qb + (size_t)b * LC + (size_t)(row0 + lr) * C_ + kk * 32 + lg * 8);

    f4v of[8];
#pragma unroll
    for (int t = 0; t < 8; ++t) of[t] = (f4v){0.f, 0.f, 0.f, 0.f};
    float mrun[4], lsum[4];
#pragma unroll
    for (int r = 0; r < 4; ++r) { mrun[r] = -1e30f; lsum[r] = 0.f; }

    short* myp = &pl[w][0];

    STAGE(0, 0);
    WAIT_VM0;
    __builtin_amdgcn_s_barrier();
    FENCE;

    int cur = 0;
    for (int mt = 0; mt < NT; ++mt) {
        if (mt + 1 < NT) STAGE(cur ^ 1, (mt + 1) * KVB);

        // ---- QK^T: 16 q-rows x 64 k-cols ----
        const char* kl = (const char*)&kb[cur][0];
        f4v s[4];
#pragma unroll
        for (int st = 0; st < 4; ++st) s[st] = (f4v){0.f, 0.f, 0.f, 0.f};
#pragma unroll
        for (int st = 0; st < 4; ++st) {
            const int row = st * 16 + lr;
            const int sw = (row & 7) << 4;
#pragma unroll
            for (int kk = 0; kk < 4; ++kk) {
                s8v kf = *(const s8v*)(kl + row * 256 + ((kk * 64 + lg * 16) ^ sw));
                s[st] = __builtin_amdgcn_mfma_f32_16x16x32_bf16(qf[kk], kf, s[st], 0, 0, 0);
            }
        }

        // ---- online softmax (rows on lg-groups, cols across lr) ----
        float al[4], p[4][4];
#pragma unroll
        for (int r = 0; r < 4; ++r) {
            float rm = fmaxf(fmaxf(s[0][r], s[1][r]), fmaxf(s[2][r], s[3][r]));
            rm = fmaxf(rm, __shfl_xor(rm, 1));
            rm = fmaxf(rm, __shfl_xor(rm, 2));
            rm = fmaxf(rm, __shfl_xor(rm, 4));
            rm = fmaxf(rm, __shfl_xor(rm, 8));
            float mn = fmaxf(mrun[r], rm);
            al[r] = __expf(mrun[r] - mn);
            float rs = 0.f;
#pragma unroll
            for (int st = 0; st < 4; ++st) { p[st][r] = __expf(s[st][r] - mn); rs += p[st][r]; }
            rs += __shfl_xor(rs, 1);
            rs += __shfl_xor(rs, 2);
            rs += __shfl_xor(rs, 4);
            rs += __shfl_xor(rs, 8);
            lsum[r] = lsum[r] * al[r] + rs;
            mrun[r] = mn;
        }
#pragma unroll
        for (int t = 0; t < 8; ++t) {
            of[t][0] *= al[0]; of[t][1] *= al[1];
            of[t][2] *= al[2]; of[t][3] *= al[3];
        }

        // ---- P (C/D layout) -> per-wave LDS -> A-frag layout ----
#pragma unroll
        for (int r = 0; r < 4; ++r) {
            const int prow = 4 * lg + r;
#pragma unroll
            for (int st = 0; st < 4; ++st)
                myp[prow * 72 + st * 16 + lr] = f2bf(p[st][r]);
        }
        s8v pf0 = *(const s8v*)(myp + lr * 72 + lg * 8);
        s8v pf1 = *(const s8v*)(myp + lr * 72 + 32 + lg * 8);

        // ---- PV ----
        const char* vl = (const char*)&vb[cur][0];
#pragma unroll
        for (int t = 0; t < 8; ++t) {
            const int c = t * 16 + lr;
            const int sw = (c & 7) << 4;
            s8v vf0 = *(const s8v*)(vl + c * 128 + ((lg * 16) ^ sw));
            s8v vf1 = *(const s8v*)(vl + c * 128 + ((64 + lg * 16) ^ sw));
            of[t] = __builtin_amdgcn_mfma_f32_16x16x32_bf16(pf0, vf0, of[t], 0, 0, 0);
            of[t] = __builtin_amdgcn_mfma_f32_16x16x32_bf16(pf1, vf1, of[t], 0, 0, 0);
        }

        WAIT_VM0;                       // prefetched tile landed (hidden under compute)
        __builtin_amdgcn_s_barrier();   // everyone done reading buf[cur]
        FENCE;
        cur ^= 1;
    }

#pragma unroll
    for (int r = 0; r < 4; ++r) lsum[r] = 1.0f / lsum[r];
#pragma unroll
    for (int t = 0; t < 8; ++t) {
#pragma unroll
        for (int r = 0; r < 4; ++r) {
            float v = of[t][r] * lsum[r];
            v = v > 0.f ? v : 0.f;
            RR[(size_t)b * LC + (size_t)(row0 + 4 * lg + r) * C_ + t * 16 + lr] = f2bf(v);
        }
    }
#undef STAGE
}

// ---------------------------------------------------------------------------
// Kernel C: out = x + Wo @ RR^T + bo   -> [B][C][L] fp32
// ---------------------------------------------------------------------------
__global__ __launch_bounds__(256) void out_proj(
    const short* __restrict__ RR, const float* __restrict__ Wo,
    const float* __restrict__ bo, const float* __restrict__ x,
    float* __restrict__ out)
{
    const int b  = blockIdx.x >> 5;
    const int l0 = (blockIdx.x & 31) * 64;
    const int tid = threadIdx.x, lane = tid & 63, w = tid >> 6;
    const int lr = lane & 15, lg = lane >> 4;
    const size_t LC = (size_t)L_ * C_;
    const int row0 = l0 + w * 16;

    s8v af[4];
#pragma unroll
    for (int kk = 0; kk < 4; ++kk)
        af[kk] = *(const s8v*)(RR + (size_t)b * LC + (size_t)(row0 + lr) * C_ + kk * 32 + lg * 8);

#pragma unroll
    for (int nt = 0; nt < 8; ++nt) {
        f4v acc = {0.f, 0.f, 0.f, 0.f};
#pragma unroll
        for (int kk = 0; kk < 4; ++kk) {
            f8v wv = *(const f8v*)(Wo + (size_t)(nt * 16 + lr) * C_ + kk * 32 + lg * 8);
            s8v wb;
#pragma unroll
            for (int j = 0; j < 8; ++j) wb[j] = f2bf(wv[j]);
            acc = __builtin_amdgcn_mfma_f32_16x16x32_bf16(af[kk], wb, acc, 0, 0, 0);
        }
        const int o = nt * 16 + lr;
        const float bias = bo[o];
        const size_t base = (size_t)b * LC + (size_t)o * L_ + row0 + 4 * lg;
        f4v xv = *(const f4v*)(x + base);
        f4v ov;
#pragma unroll
        for (int r = 0; r < 4; ++r) ov[r] = acc[r] + xv[r] + bias;
        *(f4v*)(out + base) = ov;
    }
}

extern "C" void kernel_launch(void* const* d_in, const int* in_sizes, int n_in,
                              void* d_out, int out_size, void* d_ws, size_t ws_size,
                              hipStream_t stream) {
    const float* x  = (const float*)d_in[0];
    const float* Wq = (const float*)d_in[1];
    const float* bq = (const float*)d_in[2];
    const float* Wk = (const float*)d_in[3];
    const float* bk = (const float*)d_in[4];
    const float* Wv = (const float*)d_in[5];
    const float* bv = (const float*)d_in[6];
    const float* Wo = (const float*)d_in[7];
    const float* bo = (const float*)d_in[8];
    float* out = (float*)d_out;

    const size_t NE = (size_t)B_ * L_ * C_;
    short* Qb = (short*)d_ws;
    short* Kb = Qb + NE;
    short* Vt = Kb + NE;
    short* RR = Vt + NE;

    qkv_proj<<<256, 256, 0, stream>>>(x, Wq, bq, Wk, bk, Wv, bv, Qb, Kb, Vt);
    attn    <<<256, 256, 0, stream>>>(Qb, Kb, Vt, RR);
    out_proj<<<256, 256, 0, stream>>>(RR, Wo, bo, x, out);
}

// Round 3
// 81.792 us; speedup vs baseline: 2.6025x; 1.4046x over previous
//
#include <hip/hip_runtime.h>

#define B_ 8
#define C_ 128
#define L_ 2048
#define NE (B_ * L_ * C_)

typedef __attribute__((ext_vector_type(8))) short s8v;
typedef __attribute__((ext_vector_type(4))) short s4v;
typedef __attribute__((ext_vector_type(4))) float f4v;
typedef __attribute__((ext_vector_type(8))) float f8v;

static __device__ inline short f2bf(float f) {
    union { float f; unsigned u; } v; v.f = f;
    unsigned r = v.u + 0x7FFFu + ((v.u >> 16) & 1u);
    return (short)(r >> 16);
}

static __device__ inline void gload16(const void* g, void* l) {
    __builtin_amdgcn_global_load_lds(
        (const __attribute__((address_space(1))) unsigned int*)g,
        (__attribute__((address_space(3))) unsigned int*)l, 16, 0, 0);
}

#define WAIT_VM0 asm volatile("s_waitcnt vmcnt(0)" ::: "memory")

// ---------------------------------------------------------------------------
// prep: bf16 weights (Wq pre-scaled by 1/sqrt(C)), scaled bq. grid 16x256.
// ---------------------------------------------------------------------------
__global__ __launch_bounds__(256) void prep(
    const float* __restrict__ Wq, const float* __restrict__ Wk,
    const float* __restrict__ Wv, const float* __restrict__ Wo,
    const float* __restrict__ bq, short* __restrict__ Wb, float* __restrict__ bqs)
{
    const float s = 0.08838834764831845f;  // 1/sqrt(128)
    const int i = (blockIdx.x * 256 + threadIdx.x) * 4;
    const float* src[4] = { Wq, Wk, Wv, Wo };
#pragma unroll
    for (int m = 0; m < 4; ++m) {
        f4v v = *(const f4v*)(src[m] + i);
        const float mul = (m == 0) ? s : 1.f;
        s4v o;
#pragma unroll
        for (int j = 0; j < 4; ++j) o[j] = f2bf(v[j] * mul);
        *(s4v*)(Wb + m * 16384 + i) = o;
    }
    if (blockIdx.x == 0 && threadIdx.x < C_) bqs[threadIdx.x] = bq[threadIdx.x] * s;
}

// ---------------------------------------------------------------------------
// Kernel A: h = relu(x); Q,K -> [B][L][C] bf16 ; V -> [B][C][L] bf16
// ---------------------------------------------------------------------------
__global__ __launch_bounds__(256) void qkv_proj(
    const float* __restrict__ x, const short* __restrict__ Wb,
    const float* __restrict__ bqs, const float* __restrict__ bk,
    const float* __restrict__ bv,
    short* __restrict__ Qb, short* __restrict__ Kb, short* __restrict__ Vt)
{
    __shared__ short ht[64][136];
    const int b  = blockIdx.x >> 5;
    const int l0 = (blockIdx.x & 31) * 64;
    const int tid = threadIdx.x;

    {
        const int lq = (tid & 15) * 4;
        const int cb = tid >> 4;
        for (int p = 0; p < 8; ++p) {
            int c = p * 16 + cb;
            f4v v = *(const f4v*)(x + ((size_t)b * C_ + c) * L_ + l0 + lq);
#pragma unroll
            for (int j = 0; j < 4; ++j)
                ht[lq + j][c] = f2bf(v[j] > 0.f ? v[j] : 0.f);
        }
    }
    __syncthreads();

    const int lane = tid & 63, w = tid >> 6;
    const int lr = lane & 15, lg = lane >> 4;

    s8v hf[4];
#pragma unroll
    for (int kk = 0; kk < 4; ++kk)
        hf[kk] = *(const s8v*)&ht[w * 16 + lr][kk * 32 + lg * 8];

#pragma unroll
    for (int mat = 0; mat < 3; ++mat) {
        const short* W = Wb + mat * 16384;
        const float* bias = (mat == 0) ? bqs : (mat == 1 ? bk : bv);
#pragma unroll
        for (int nt = 0; nt < 8; ++nt) {
            f4v acc = {0.f, 0.f, 0.f, 0.f};
#pragma unroll
            for (int kk = 0; kk < 4; ++kk) {
                s8v wfr = *(const s8v*)(W + (size_t)(nt * 16 + lr) * C_ + kk * 32 + lg * 8);
                acc = __builtin_amdgcn_mfma_f32_16x16x32_bf16(hf[kk], wfr, acc, 0, 0, 0);
            }
            const int o = nt * 16 + lr;
            const float bsc = bias[o];
            const int row = l0 + w * 16 + 4 * lg;
            if (mat == 0) {
#pragma unroll
                for (int r = 0; r < 4; ++r)
                    Qb[((size_t)b * L_ + row + r) * C_ + o] = f2bf(acc[r] + bsc);
            } else if (mat == 1) {
#pragma unroll
                for (int r = 0; r < 4; ++r)
                    Kb[((size_t)b * L_ + row + r) * C_ + o] = f2bf(acc[r] + bsc);
            } else {
                s4v pk;
#pragma unroll
                for (int r = 0; r < 4; ++r) pk[r] = f2bf(acc[r] + bsc);
                *(s4v*)(Vt + ((size_t)b * C_ + o) * L_ + row) = pk;
            }
        }
    }
}

// ---------------------------------------------------------------------------
// Kernel B: flash attention, fixed-shift softmax (p = exp(S-8)), unnormalized
// partial sums. Grid 512 = [half][qt][b]; 4 waves = [rowhalf][tile-parity].
// Writes A-partials (fp32) + l-partials per half; parity merged in-block.
// ---------------------------------------------------------------------------
#define KVB 32
#define NSTEP 16    // 2 tiles per step, 32 tiles per block (= half of L)

__global__ __launch_bounds__(256, 2) void attn(
    const short* __restrict__ Qb, const short* __restrict__ Kb,
    const short* __restrict__ Vt, float* __restrict__ Ap, float* __restrict__ lp)
{
    __shared__ short kbuf[2][2][KVB * C_];   // [phase][parity], 8KB each
    __shared__ short vbuf[2][2][C_ * KVB];
    __shared__ short pbuf[4][32 * 40];       // per-wave P, pitch 40 shorts (80B)

    const int b    = blockIdx.x & 7;
    const int qt   = (blockIdx.x >> 3) & 31;
    const int half = blockIdx.x >> 8;
    const int q0   = qt * 64;
    const int tid = threadIdx.x, lane = tid & 63, w = tid >> 6;
    const int lr = lane & 15, lg = lane >> 4;
    const int rh = w >> 1, par = w & 1;
    const size_t LC = (size_t)L_ * C_;

    const char* KB = (const char*)(Kb + (size_t)b * LC);
    const char* VB = (const char*)(Vt + (size_t)b * LC);
    const int t0 = half * 32;

    // staging offsets: K rows 256B (XOR-swizzled source, linear LDS dest);
    // V rows 64B (natural layout, no swizzle needed)
    int ksrc[2], vsrc[2], dsto[2];
#pragma unroll
    for (int i2 = 0; i2 < 2; ++i2) {
        const int p = w * 1024 + i2 * 4096 + lane * 16;
        dsto[i2] = w * 1024 + i2 * 4096;
        const int krow = p >> 8, kcol = p & 255;
        ksrc[i2] = krow * 256 + (kcol ^ ((krow & 7) << 4));
        vsrc[i2] = (p >> 6) * (L_ * 2) + (p & 63);
    }
    char* kls = (char*)&kbuf[0][0][0];
    char* vls = (char*)&vbuf[0][0][0];

#define STAGE(PH, TILE) do {                                                   \
    _Pragma("unroll")                                                          \
    for (int pr_ = 0; pr_ < 2; ++pr_) {                                        \
        const int m0_ = ((TILE) + pr_) * KVB;                                  \
        char* kd_ = kls + (PH) * 16384 + pr_ * 8192;                           \
        char* vd_ = vls + (PH) * 16384 + pr_ * 8192;                           \
        _Pragma("unroll")                                                      \
        for (int i2_ = 0; i2_ < 2; ++i2_) {                                    \
            gload16(KB + (size_t)m0_ * 256 + ksrc[i2_], kd_ + dsto[i2_]);      \
            gload16(VB + (size_t)m0_ * 2   + vsrc[i2_], vd_ + dsto[i2_]);      \
        }                                                                      \
    } } while (0)

    // Q fragments: rows q0 + rh*32 + rg*16 + lr
    s8v qf[2][4];
#pragma unroll
    for (int rg = 0; rg < 2; ++rg)
#pragma unroll
        for (int kk = 0; kk < 4; ++kk)
            qf[rg][kk] = *(const s8v*)(Qb + (size_t)b * LC
                          + (size_t)(q0 + rh * 32 + rg * 16 + lr) * C_ + kk * 32 + lg * 8);

    f4v of[2][8];
    float lsum[2][4];
#pragma unroll
    for (int rg = 0; rg < 2; ++rg) {
#pragma unroll
        for (int t = 0; t < 8; ++t) of[rg][t] = (f4v){0.f, 0.f, 0.f, 0.f};
#pragma unroll
        for (int r = 0; r < 4; ++r) lsum[rg][r] = 0.f;
    }

    short* myp = &pbuf[w][0];
    const char* klp = kls + par * 8192;
    const char* vlp = vls + par * 8192;

    STAGE(0, t0);
    WAIT_VM0;
    __builtin_amdgcn_s_barrier();

#define STEP(PH, J) do {                                                       \
    if ((J) + 1 < NSTEP) STAGE((PH) ^ 1, t0 + 2 * ((J) + 1));                  \
    const char* kl_ = klp + (PH) * 16384;                                      \
    const char* vl_ = vlp + (PH) * 16384;                                      \
    f4v sc[2][2];                                                              \
    sc[0][0] = sc[0][1] = sc[1][0] = sc[1][1] = (f4v){0.f, 0.f, 0.f, 0.f};     \
    const int sw_ = (lr & 7) << 4;                                             \
    _Pragma("unroll")                                                          \
    for (int st = 0; st < 2; ++st) {                                           \
        _Pragma("unroll")                                                      \
        for (int kk = 0; kk < 4; ++kk) {                                       \
            s8v kf = *(const s8v*)(kl_ + (st * 16 + lr) * 256                  \
                                   + ((kk * 64 + lg * 16) ^ sw_));             \
            sc[0][st] = __builtin_amdgcn_mfma_f32_16x16x32_bf16(qf[0][kk], kf, sc[0][st], 0, 0, 0); \
            sc[1][st] = __builtin_amdgcn_mfma_f32_16x16x32_bf16(qf[1][kk], kf, sc[1][st], 0, 0, 0); \
        }                                                                      \
    }                                                                          \
    _Pragma("unroll")                                                          \
    for (int rg = 0; rg < 2; ++rg)                                             \
    _Pragma("unroll")                                                          \
    for (int st = 0; st < 2; ++st)                                             \
    _Pragma("unroll")                                                          \
    for (int r = 0; r < 4; ++r) {                                              \
        float pv = __expf(sc[rg][st][r] - 8.0f);                               \
        lsum[rg][r] += pv;                                                     \
        myp[(rg * 16 + 4 * lg + r) * 40 + st * 16 + lr] = f2bf(pv);            \
    }                                                                          \
    s8v pf0 = *(const s8v*)(myp + lr * 40 + lg * 8);                           \
    s8v pf1 = *(const s8v*)(myp + (16 + lr) * 40 + lg * 8);                    \
    _Pragma("unroll")                                                          \
    for (int t = 0; t < 8; ++t) {                                              \
        s8v vf = *(const s8v*)(vl_ + (t * 16 + lr) * 64 + lg * 16);            \
        of[0][t] = __builtin_amdgcn_mfma_f32_16x16x32_bf16(pf0, vf, of[0][t], 0, 0, 0); \
        of[1][t] = __builtin_amdgcn_mfma_f32_16x16x32_bf16(pf1, vf, of[1][t], 0, 0, 0); \
    }                                                                          \
    WAIT_VM0;                                                                  \
    __builtin_amdgcn_s_barrier();                                              \
    } while (0)

#pragma unroll 1
    for (int j = 0; j < NSTEP; j += 2) {
        STEP(0, j);
        STEP(1, j + 1);
    }

    // reduce l across the 16 k-col lanes
#pragma unroll
    for (int rg = 0; rg < 2; ++rg)
#pragma unroll
    for (int r = 0; r < 4; ++r) {
        float v = lsum[rg][r];
        v += __shfl_xor(v, 1);
        v += __shfl_xor(v, 2);
        v += __shfl_xor(v, 4);
        v += __shfl_xor(v, 8);
        lsum[rg][r] = v;
    }

    // parity merge via freed K/V LDS
    float* mrg  = (float*)kls;   // [rh][32][128] fp32 = 32KB
    float* mrgl = (float*)vls;   // 64 floats
    if (par == 0) {
#pragma unroll
        for (int rg = 0; rg < 2; ++rg)
#pragma unroll
        for (int t = 0; t < 8; ++t)
#pragma unroll
        for (int r = 0; r < 4; ++r)
            mrg[rh * 4096 + (rg * 16 + 4 * lg + r) * 128 + t * 16 + lr] = of[rg][t][r];
        if (lr == 0) {
#pragma unroll
            for (int rg = 0; rg < 2; ++rg)
#pragma unroll
            for (int r = 0; r < 4; ++r)
                mrgl[rh * 32 + rg * 16 + 4 * lg + r] = lsum[rg][r];
        }
    }
    __syncthreads();
    if (par == 1) {
#pragma unroll
        for (int rg = 0; rg < 2; ++rg) {
#pragma unroll
            for (int t = 0; t < 8; ++t)
#pragma unroll
            for (int r = 0; r < 4; ++r)
                of[rg][t][r] += mrg[rh * 4096 + (rg * 16 + 4 * lg + r) * 128 + t * 16 + lr];
#pragma unroll
            for (int r = 0; r < 4; ++r)
                lsum[rg][r] += mrgl[rh * 32 + rg * 16 + 4 * lg + r];
        }
        float* Abase = Ap + (size_t)(half * B_ + b) * LC;
        float* lbase = lp + (size_t)(half * B_ + b) * L_;
#pragma unroll
        for (int rg = 0; rg < 2; ++rg)
#pragma unroll
        for (int r = 0; r < 4; ++r) {
            const int row = q0 + rh * 32 + rg * 16 + 4 * lg + r;
#pragma unroll
            for (int t = 0; t < 8; ++t)
                Abase[(size_t)row * C_ + t * 16 + lr] = of[rg][t][r];
            if (lr == 0) lbase[row] = lsum[rg][r];
        }
    }
#undef STEP
#undef STAGE
}

// ---------------------------------------------------------------------------
// Kernel C: R = relu((A0+A1)/(l0+l1)); out = x + Wo R^T + bo
// ---------------------------------------------------------------------------
__global__ __launch_bounds__(256) void out_proj(
    const float* __restrict__ Ap, const float* __restrict__ lp,
    const short* __restrict__ Wb, const float* __restrict__ bo,
    const float* __restrict__ x, float* __restrict__ out)
{
    const int b  = blockIdx.x >> 5;
    const int l0 = (blockIdx.x & 31) * 64;
    const int tid = threadIdx.x, lane = tid & 63, w = tid >> 6;
    const int lr = lane & 15, lg = lane >> 4;
    const size_t LC = (size_t)L_ * C_;
    const int row = l0 + w * 16 + lr;

    const float* A0 = Ap + ((size_t)b * L_ + row) * C_;
    const float* A1 = A0 + (size_t)B_ * L_ * C_;
    const float linv = 1.0f / (lp[(size_t)b * L_ + row] + lp[(size_t)(B_ + b) * L_ + row]);

    s8v af[4];
#pragma unroll
    for (int kk = 0; kk < 4; ++kk) {
        f8v a0 = *(const f8v*)(A0 + kk * 32 + lg * 8);
        f8v a1 = *(const f8v*)(A1 + kk * 32 + lg * 8);
#pragma unroll
        for (int j = 0; j < 8; ++j) {
            float v = a0[j] + a1[j];
            v = fmaxf(v, 0.f) * linv;
            af[kk][j] = f2bf(v);
        }
    }

    const short* Wo_b = Wb + 3 * 16384;
#pragma unroll
    for (int nt = 0; nt < 8; ++nt) {
        f4v acc = {0.f, 0.f, 0.f, 0.f};
#pragma unroll
        for (int kk = 0; kk < 4; ++kk) {
            s8v wfr = *(const s8v*)(Wo_b + (size_t)(nt * 16 + lr) * C_ + kk * 32 + lg * 8);
            acc = __builtin_amdgcn_mfma_f32_16x16x32_bf16(af[kk], wfr, acc, 0, 0, 0);
        }
        const int o = nt * 16 + lr;
        const float bias = bo[o];
        const size_t base = (size_t)b * LC + (size_t)o * L_ + l0 + w * 16 + 4 * lg;
        f4v xv = *(const f4v*)(x + base);
        f4v ov;
#pragma unroll
        for (int r = 0; r < 4; ++r) ov[r] = acc[r] + xv[r] + bias;
        *(f4v*)(out + base) = ov;
    }
}

extern "C" void kernel_launch(void* const* d_in, const int* in_sizes, int n_in,
                              void* d_out, int out_size, void* d_ws, size_t ws_size,
                              hipStream_t stream) {
    const float* x  = (const float*)d_in[0];
    const float* Wq = (const float*)d_in[1];
    const float* bq = (const float*)d_in[2];
    const float* Wk = (const float*)d_in[3];
    const float* bk = (const float*)d_in[4];
    const float* Wv = (const float*)d_in[5];
    const float* bv = (const float*)d_in[6];
    const float* Wo = (const float*)d_in[7];
    const float* bo = (const float*)d_in[8];
    float* out = (float*)d_out;

    short* Qb  = (short*)d_ws;            // NE bf16
    short* Kb  = Qb + NE;                 // NE bf16
    short* Vt  = Kb + NE;                 // NE bf16 (transposed)
    short* Wb  = Vt + NE;                 // 4*16384 bf16 weights
    float* bqs = (float*)(Wb + 4 * 16384);// 128 fp32
    float* Ap  = bqs + 128;               // 2*NE fp32 partial A
    float* lp  = Ap + 2 * (size_t)NE;     // 2*B*L fp32 partial l

    prep    <<<16,  256, 0, stream>>>(Wq, Wk, Wv, Wo, bq, Wb, bqs);
    qkv_proj<<<256, 256, 0, stream>>>(x, Wb, bqs, bk, bv, Qb, Kb, Vt);
    attn    <<<512, 256, 0, stream>>>(Qb, Kb, Vt, Ap, lp);
    out_proj<<<256, 256, 0, stream>>>(Ap, lp, Wb, bo, x, out);
}

// Round 4
// 70.389 us; speedup vs baseline: 3.0241x; 1.1620x over previous
//
#include <hip/hip_runtime.h>

#define B_ 8
#define C_ 128
#define L_ 2048
#define NE (B_ * L_ * C_)

typedef __attribute__((ext_vector_type(8))) short s8v;
typedef __attribute__((ext_vector_type(4))) short s4v;
typedef __attribute__((ext_vector_type(4))) float f4v;
typedef __attribute__((ext_vector_type(8))) float f8v;

// 1/sqrt(128) * log2(e)  (folded into Wq/bq so attn can use exp2 directly)
#define QSCALE 0.1275174106f
// 8 * log2(e)
#define ESHIFT 11.5415603272f

static __device__ inline short f2bf(float f) {
    union { float f; unsigned u; } v; v.f = f;
    unsigned r = v.u + 0x7FFFu + ((v.u >> 16) & 1u);
    return (short)(r >> 16);
}

static __device__ inline unsigned cvt_pk_bf16(float lo, float hi) {
    unsigned r;
    asm("v_cvt_pk_bf16_f32 %0, %1, %2" : "=v"(r) : "v"(lo), "v"(hi));
    return r;
}

static __device__ inline void gload16(const void* g, void* l) {
    __builtin_amdgcn_global_load_lds(
        (const __attribute__((address_space(1))) unsigned int*)g,
        (__attribute__((address_space(3))) unsigned int*)l, 16, 0, 0);
}

#define WAIT_VM0 asm volatile("s_waitcnt vmcnt(0)" ::: "memory")

// ---------------------------------------------------------------------------
// prep: bf16 weights (Wq pre-scaled by QSCALE), scaled bq. grid 16x256.
// ---------------------------------------------------------------------------
__global__ __launch_bounds__(256) void prep(
    const float* __restrict__ Wq, const float* __restrict__ Wk,
    const float* __restrict__ Wv, const float* __restrict__ Wo,
    const float* __restrict__ bq, short* __restrict__ Wb, float* __restrict__ bqs)
{
    const int i = (blockIdx.x * 256 + threadIdx.x) * 4;
    const float* src[4] = { Wq, Wk, Wv, Wo };
#pragma unroll
    for (int m = 0; m < 4; ++m) {
        f4v v = *(const f4v*)(src[m] + i);
        const float mul = (m == 0) ? QSCALE : 1.f;
        union { s4v s; unsigned u[2]; } o;
        o.u[0] = cvt_pk_bf16(v[0] * mul, v[1] * mul);
        o.u[1] = cvt_pk_bf16(v[2] * mul, v[3] * mul);
        *(s4v*)(Wb + m * 16384 + i) = o.s;
    }
    if (blockIdx.x == 0 && threadIdx.x < C_) bqs[threadIdx.x] = bq[threadIdx.x] * QSCALE;
}

// ---------------------------------------------------------------------------
// Kernel A: h = relu(x); Q,K -> [B][L][C] bf16 ; V -> [B][C][L] bf16
// grid 1024 = b(8) x 128 l-tiles of 16 rows; 4 waves each own 6 (mat,nt) tiles
// ---------------------------------------------------------------------------
__global__ __launch_bounds__(256) void qkv_proj(
    const float* __restrict__ x, const short* __restrict__ Wb,
    const float* __restrict__ bqs, const float* __restrict__ bk,
    const float* __restrict__ bv,
    short* __restrict__ Qb, short* __restrict__ Kb, short* __restrict__ Vt)
{
    __shared__ short ht[16][136];
    const int b  = blockIdx.x >> 7;
    const int l0 = (blockIdx.x & 127) * 16;
    const int tid = threadIdx.x;

    {
        const int c = tid >> 1, lh = (tid & 1) * 8;
        f8v v = *(const f8v*)(x + ((size_t)b * C_ + c) * L_ + l0 + lh);
#pragma unroll
        for (int j = 0; j < 8; ++j) ht[lh + j][c] = f2bf(fmaxf(v[j], 0.f));
    }
    __syncthreads();

    const int lane = tid & 63, w = tid >> 6;
    const int lr = lane & 15, lg = lane >> 4;

    s8v hf[4];
#pragma unroll
    for (int kk = 0; kk < 4; ++kk)
        hf[kk] = *(const s8v*)&ht[lr][kk * 32 + lg * 8];

#pragma unroll
    for (int i = 0; i < 6; ++i) {
        const int idx = w * 6 + i;
        const int mat = idx >> 3, nt = idx & 7;
        const short* W = Wb + mat * 16384;
        f4v acc = {0.f, 0.f, 0.f, 0.f};
#pragma unroll
        for (int kk = 0; kk < 4; ++kk) {
            s8v wfr = *(const s8v*)(W + (size_t)(nt * 16 + lr) * C_ + kk * 32 + lg * 8);
            acc = __builtin_amdgcn_mfma_f32_16x16x32_bf16(hf[kk], wfr, acc, 0, 0, 0);
        }
        const int o = nt * 16 + lr;
        const float bsc = (mat == 0 ? bqs : (mat == 1 ? bk : bv))[o];
        if (mat == 0) {
#pragma unroll
            for (int r = 0; r < 4; ++r)
                Qb[((size_t)b * L_ + l0 + 4 * lg + r) * C_ + o] = f2bf(acc[r] + bsc);
        } else if (mat == 1) {
#pragma unroll
            for (int r = 0; r < 4; ++r)
                Kb[((size_t)b * L_ + l0 + 4 * lg + r) * C_ + o] = f2bf(acc[r] + bsc);
        } else {
            union { s4v s; unsigned u[2]; } pk;
            pk.u[0] = cvt_pk_bf16(acc[0] + bsc, acc[1] + bsc);
            pk.u[1] = cvt_pk_bf16(acc[2] + bsc, acc[3] + bsc);
            *(s4v*)(Vt + ((size_t)b * C_ + o) * L_ + l0 + 4 * lg) = pk.s;
        }
    }
}

// ---------------------------------------------------------------------------
// Kernel B: flash attention, fixed-shift exp2 softmax (p = 2^(S'-8*log2e)),
// unnormalized partial sums. Grid 512 = [half][qt][b]; waves = rowhalf x parity.
// ---------------------------------------------------------------------------
#define KVB 32
#define NSTEP 16

__global__ __launch_bounds__(256, 2) void attn(
    const short* __restrict__ Qb, const short* __restrict__ Kb,
    const short* __restrict__ Vt, float* __restrict__ Ap, float* __restrict__ lp)
{
    __shared__ short kbuf[2][2][KVB * C_];
    __shared__ short vbuf[2][2][C_ * KVB];
    __shared__ short pbuf[4][32 * 40];

    const int b    = blockIdx.x & 7;
    const int qt   = (blockIdx.x >> 3) & 31;
    const int half = blockIdx.x >> 8;
    const int q0   = qt * 64;
    const int tid = threadIdx.x, lane = tid & 63, w = tid >> 6;
    const int lr = lane & 15, lg = lane >> 4;
    const int rh = w >> 1, par = w & 1;
    const size_t LC = (size_t)L_ * C_;

    const char* KB = (const char*)(Kb + (size_t)b * LC);
    const char* VB = (const char*)(Vt + (size_t)b * LC);
    const int t0 = half * 32;

    int ksrc[2], vsrc[2], dsto[2];
#pragma unroll
    for (int i2 = 0; i2 < 2; ++i2) {
        const int p = w * 1024 + i2 * 4096 + lane * 16;
        dsto[i2] = w * 1024 + i2 * 4096;
        const int krow = p >> 8, kcol = p & 255;
        ksrc[i2] = krow * 256 + (kcol ^ ((krow & 7) << 4));
        vsrc[i2] = (p >> 6) * (L_ * 2) + (p & 63);
    }
    char* kls = (char*)&kbuf[0][0][0];
    char* vls = (char*)&vbuf[0][0][0];

#define STAGE(PH, TILE) do {                                                   \
    _Pragma("unroll")                                                          \
    for (int pr_ = 0; pr_ < 2; ++pr_) {                                        \
        const int m0_ = ((TILE) + pr_) * KVB;                                  \
        char* kd_ = kls + (PH) * 16384 + pr_ * 8192;                           \
        char* vd_ = vls + (PH) * 16384 + pr_ * 8192;                           \
        _Pragma("unroll")                                                      \
        for (int i2_ = 0; i2_ < 2; ++i2_) {                                    \
            gload16(KB + (size_t)m0_ * 256 + ksrc[i2_], kd_ + dsto[i2_]);      \
            gload16(VB + (size_t)m0_ * 2   + vsrc[i2_], vd_ + dsto[i2_]);      \
        }                                                                      \
    } } while (0)

    s8v qf[2][4];
#pragma unroll
    for (int rg = 0; rg < 2; ++rg)
#pragma unroll
        for (int kk = 0; kk < 4; ++kk)
            qf[rg][kk] = *(const s8v*)(Qb + (size_t)b * LC
                          + (size_t)(q0 + rh * 32 + rg * 16 + lr) * C_ + kk * 32 + lg * 8);

    f4v of[2][8];
    float lsum[2][4];
#pragma unroll
    for (int rg = 0; rg < 2; ++rg) {
#pragma unroll
        for (int t = 0; t < 8; ++t) of[rg][t] = (f4v){0.f, 0.f, 0.f, 0.f};
#pragma unroll
        for (int r = 0; r < 4; ++r) lsum[rg][r] = 0.f;
    }

    short* myp = &pbuf[w][0];
    const char* klp = kls + par * 8192;
    const char* vlp = vls + par * 8192;

    STAGE(0, t0);
    WAIT_VM0;
    __builtin_amdgcn_s_barrier();

#define STEP(PH, J) do {                                                       \
    if ((J) + 1 < NSTEP) STAGE((PH) ^ 1, t0 + 2 * ((J) + 1));                  \
    const char* kl_ = klp + (PH) * 16384;                                      \
    const char* vl_ = vlp + (PH) * 16384;                                      \
    f4v sc[2][2];                                                              \
    sc[0][0] = sc[0][1] = sc[1][0] = sc[1][1] = (f4v){0.f, 0.f, 0.f, 0.f};     \
    const int sw_ = (lr & 7) << 4;                                             \
    _Pragma("unroll")                                                          \
    for (int st = 0; st < 2; ++st) {                                           \
        _Pragma("unroll")                                                      \
        for (int kk = 0; kk < 4; ++kk) {                                       \
            s8v kf = *(const s8v*)(kl_ + (st * 16 + lr) * 256                  \
                                   + ((kk * 64 + lg * 16) ^ sw_));             \
            sc[0][st] = __builtin_amdgcn_mfma_f32_16x16x32_bf16(qf[0][kk], kf, sc[0][st], 0, 0, 0); \
            sc[1][st] = __builtin_amdgcn_mfma_f32_16x16x32_bf16(qf[1][kk], kf, sc[1][st], 0, 0, 0); \
        }                                                                      \
    }                                                                          \
    float pp[2][2][4];                                                         \
    _Pragma("unroll")                                                          \
    for (int rg = 0; rg < 2; ++rg)                                             \
    _Pragma("unroll")                                                          \
    for (int st = 0; st < 2; ++st)                                             \
    _Pragma("unroll")                                                          \
    for (int r = 0; r < 4; ++r) {                                              \
        float pv = __builtin_amdgcn_exp2f(sc[rg][st][r] - ESHIFT);             \
        lsum[rg][r] += pv;                                                     \
        pp[rg][st][r] = pv;                                                    \
    }                                                                          \
    _Pragma("unroll")                                                          \
    for (int rg = 0; rg < 2; ++rg)                                             \
    _Pragma("unroll")                                                          \
    for (int r = 0; r < 4; ++r) {                                              \
        const unsigned pk_ = cvt_pk_bf16(pp[rg][0][r], pp[rg][1][r]);          \
        const int prow_ = (rg * 16 + 4 * lg + r) * 40;                         \
        myp[prow_ + lr]      = (short)(pk_ & 0xffff);                          \
        myp[prow_ + 16 + lr] = (short)(pk_ >> 16);                             \
    }                                                                          \
    s8v pf0 = *(const s8v*)(myp + lr * 40 + lg * 8);                           \
    s8v pf1 = *(const s8v*)(myp + (16 + lr) * 40 + lg * 8);                    \
    _Pragma("unroll")                                                          \
    for (int t = 0; t < 8; ++t) {                                              \
        s8v vf = *(const s8v*)(vl_ + (t * 16 + lr) * 64 + lg * 16);            \
        of[0][t] = __builtin_amdgcn_mfma_f32_16x16x32_bf16(pf0, vf, of[0][t], 0, 0, 0); \
        of[1][t] = __builtin_amdgcn_mfma_f32_16x16x32_bf16(pf1, vf, of[1][t], 0, 0, 0); \
    }                                                                          \
    WAIT_VM0;                                                                  \
    __builtin_amdgcn_s_barrier();                                              \
    } while (0)

#pragma unroll 1
    for (int j = 0; j < NSTEP; j += 2) {
        STEP(0, j);
        STEP(1, j + 1);
    }

#pragma unroll
    for (int rg = 0; rg < 2; ++rg)
#pragma unroll
    for (int r = 0; r < 4; ++r) {
        float v = lsum[rg][r];
        v += __shfl_xor(v, 1);
        v += __shfl_xor(v, 2);
        v += __shfl_xor(v, 4);
        v += __shfl_xor(v, 8);
        lsum[rg][r] = v;
    }

    float* mrg  = (float*)kls;
    float* mrgl = (float*)vls;
    if (par == 0) {
#pragma unroll
        for (int rg = 0; rg < 2; ++rg)
#pragma unroll
        for (int t = 0; t < 8; ++t)
#pragma unroll
        for (int r = 0; r < 4; ++r)
            mrg[rh * 4096 + (rg * 16 + 4 * lg + r) * 128 + t * 16 + lr] = of[rg][t][r];
        if (lr == 0) {
#pragma unroll
            for (int rg = 0; rg < 2; ++rg)
#pragma unroll
            for (int r = 0; r < 4; ++r)
                mrgl[rh * 32 + rg * 16 + 4 * lg + r] = lsum[rg][r];
        }
    }
    __syncthreads();
    if (par == 1) {
#pragma unroll
        for (int rg = 0; rg < 2; ++rg) {
#pragma unroll
            for (int t = 0; t < 8; ++t)
#pragma unroll
            for (int r = 0; r < 4; ++r)
                of[rg][t][r] += mrg[rh * 4096 + (rg * 16 + 4 * lg + r) * 128 + t * 16 + lr];
#pragma unroll
            for (int r = 0; r < 4; ++r)
                lsum[rg][r] += mrgl[rh * 32 + rg * 16 + 4 * lg + r];
        }
        float* Abase = Ap + (size_t)(half * B_ + b) * LC;
        float* lbase = lp + (size_t)(half * B_ + b) * L_;
#pragma unroll
        for (int rg = 0; rg < 2; ++rg)
#pragma unroll
        for (int r = 0; r < 4; ++r) {
            const int row = q0 + rh * 32 + rg * 16 + 4 * lg + r;
#pragma unroll
            for (int t = 0; t < 8; ++t)
                Abase[(size_t)row * C_ + t * 16 + lr] = of[rg][t][r];
            if (lr == 0) lbase[row] = lsum[rg][r];
        }
    }
#undef STEP
#undef STAGE
}

// ---------------------------------------------------------------------------
// Kernel C: R = relu((A0+A1))/(l0+l1); out = x + Wo R^T + bo
// grid 512 = b(8) x 64 l-tiles of 32 rows; waves = rowhalf x nt-half
// ---------------------------------------------------------------------------
__global__ __launch_bounds__(256) void out_proj(
    const float* __restrict__ Ap, const float* __restrict__ lp,
    const short* __restrict__ Wb, const float* __restrict__ bo,
    const float* __restrict__ x, float* __restrict__ out)
{
    const int b  = blockIdx.x >> 6;
    const int l0 = (blockIdx.x & 63) * 32;
    const int tid = threadIdx.x, lane = tid & 63, w = tid >> 6;
    const int lr = lane & 15, lg = lane >> 4;
    const int rh = w >> 1, nh = w & 1;
    const size_t LC = (size_t)L_ * C_;
    const int row = l0 + rh * 16 + lr;

    const float* A0 = Ap + ((size_t)b * L_ + row) * C_;
    const float* A1 = A0 + (size_t)NE;
    const float linv = 1.0f / (lp[(size_t)b * L_ + row] + lp[(size_t)(B_ + b) * L_ + row]);

    s8v af[4];
#pragma unroll
    for (int kk = 0; kk < 4; ++kk) {
        f8v a0 = *(const f8v*)(A0 + kk * 32 + lg * 8);
        f8v a1 = *(const f8v*)(A1 + kk * 32 + lg * 8);
        union { s8v s; unsigned u[4]; } uf;
#pragma unroll
        for (int j2 = 0; j2 < 4; ++j2) {
            float v0 = fmaxf(a0[2 * j2]     + a1[2 * j2],     0.f) * linv;
            float v1 = fmaxf(a0[2 * j2 + 1] + a1[2 * j2 + 1], 0.f) * linv;
            uf.u[j2] = cvt_pk_bf16(v0, v1);
        }
        af[kk] = uf.s;
    }

    const short* Wo_b = Wb + 3 * 16384;
#pragma unroll
    for (int i = 0; i < 4; ++i) {
        const int nt = nh * 4 + i;
        f4v acc = {0.f, 0.f, 0.f, 0.f};
#pragma unroll
        for (int kk = 0; kk < 4; ++kk) {
            s8v wfr = *(const s8v*)(Wo_b + (size_t)(nt * 16 + lr) * C_ + kk * 32 + lg * 8);
            acc = __builtin_amdgcn_mfma_f32_16x16x32_bf16(af[kk], wfr, acc, 0, 0, 0);
        }
        const int o = nt * 16 + lr;
        const float bias = bo[o];
        const size_t base = (size_t)b * LC + (size_t)o * L_ + l0 + rh * 16 + 4 * lg;
        f4v xv = *(const f4v*)(x + base);
        f4v ov;
#pragma unroll
        for (int r = 0; r < 4; ++r) ov[r] = acc[r] + xv[r] + bias;
        *(f4v*)(out + base) = ov;
    }
}

extern "C" void kernel_launch(void* const* d_in, const int* in_sizes, int n_in,
                              void* d_out, int out_size, void* d_ws, size_t ws_size,
                              hipStream_t stream) {
    const float* x  = (const float*)d_in[0];
    const float* Wq = (const float*)d_in[1];
    const float* bq = (const float*)d_in[2];
    const float* Wk = (const float*)d_in[3];
    const float* bk = (const float*)d_in[4];
    const float* Wv = (const float*)d_in[5];
    const float* bv = (const float*)d_in[6];
    const float* Wo = (const float*)d_in[7];
    const float* bo = (const float*)d_in[8];
    float* out = (float*)d_out;

    short* Qb  = (short*)d_ws;
    short* Kb  = Qb + NE;
    short* Vt  = Kb + NE;
    short* Wb  = Vt + NE;
    float* bqs = (float*)(Wb + 4 * 16384);
    float* Ap  = bqs + 128;
    float* lp  = Ap + 2 * (size_t)NE;

    prep    <<<16,   256, 0, stream>>>(Wq, Wk, Wv, Wo, bq, Wb, bqs);
    qkv_proj<<<1024, 256, 0, stream>>>(x, Wb, bqs, bk, bv, Qb, Kb, Vt);
    attn    <<<512,  256, 0, stream>>>(Qb, Kb, Vt, Ap, lp);
    out_proj<<<512,  256, 0, stream>>>(Ap, lp, Wb, bo, x, out);
}